// Round 5
// baseline (815.145 us; speedup 1.0000x reference)
//
#include <hip/hip_runtime.h>
#include <hip/hip_bf16.h>

#define N_NODES 100000
#define N_EDGES 1600000
#define DIM 64
#define NBUCK 25000            // buckets of 4 nodes (t>>2)

typedef __attribute__((ext_vector_type(8))) short bf16x8;
typedef __attribute__((ext_vector_type(4))) float f32x4;

__device__ __forceinline__ float b2f(unsigned int u16) {
    return __uint_as_float(u16 << 16);
}
__device__ __forceinline__ unsigned short f2bs(float f) {
    __hip_bfloat16 h = __float2bfloat16(f);
    return *reinterpret_cast<unsigned short*>(&h);
}

// K1 (MFMA): XsB = bf16(x @ Wm[0:64]), XtB = bf16(x @ Wm[64:128] + b), xB = bf16(x).
// Also zeroes bcnt[] (ws poisoned; must re-init every call).
__global__ __launch_bounds__(256) void node_transform(
    const float* __restrict__ x, const float* __restrict__ W_msg,
    const float* __restrict__ b_msg,
    unsigned short* __restrict__ XsB, unsigned short* __restrict__ XtB,
    unsigned short* __restrict__ xB, int* __restrict__ bcnt)
{
    __shared__ unsigned short WB[8192];   // [ct(8)][kk(2)][lane(64)][j(8)]
    const int tid = threadIdx.x;
    const int gtid = blockIdx.x * 256 + tid;
    if (gtid < NBUCK) bcnt[gtid] = 0;

    for (int i = tid; i < 8192; i += 256) {
        const int j = i & 7, l = (i >> 3) & 63, kk = (i >> 9) & 1, ct = i >> 10;
        const int k = kk * 32 + ((l >> 4) << 3) + j;     // [0,64)
        const int c = ct * 16 + (l & 15);                // [0,128)
        WB[i] = f2bs(W_msg[(((c >> 6) << 6) + k) * 64 + (c & 63)]);
    }
    __syncthreads();

    const int lane = tid & 63, w = tid >> 6;
    const int r0 = blockIdx.x * 64 + w * 16;
    if (r0 >= N_NODES) return;

    f32x4 acc[8];
    #pragma unroll
    for (int ct = 0; ct < 8; ++ct) acc[ct] = (f32x4){0.f, 0.f, 0.f, 0.f};

    const int r = r0 + (lane & 15);
    #pragma unroll
    for (int kk = 0; kk < 2; ++kk) {
        const int off = kk * 32 + ((lane >> 4) << 3);
        const float4* xp = reinterpret_cast<const float4*>(&x[r * 64 + off]);
        const float4 p0 = xp[0], p1 = xp[1];
        bf16x8 a;
        a[0] = (short)f2bs(p0.x); a[1] = (short)f2bs(p0.y);
        a[2] = (short)f2bs(p0.z); a[3] = (short)f2bs(p0.w);
        a[4] = (short)f2bs(p1.x); a[5] = (short)f2bs(p1.y);
        a[6] = (short)f2bs(p1.z); a[7] = (short)f2bs(p1.w);
        *reinterpret_cast<bf16x8*>(&xB[r * 64 + off]) = a;
        #pragma unroll
        for (int ct = 0; ct < 8; ++ct) {
            const bf16x8 b = *reinterpret_cast<const bf16x8*>(
                &WB[(((ct << 1) | kk) * 64 + lane) << 3]);
            acc[ct] = __builtin_amdgcn_mfma_f32_16x16x32_bf16(a, b, acc[ct], 0, 0, 0);
        }
    }

    const int rb = r0 + ((lane >> 4) << 2);
    #pragma unroll
    for (int ct = 0; ct < 8; ++ct) {
        const int c = ct * 16 + (lane & 15);
        if (c < 64) {
            #pragma unroll
            for (int q = 0; q < 4; ++q)
                XsB[(rb + q) * 64 + c] = f2bs(acc[ct][q]);
        } else {
            const float bj = b_msg[c - 64];
            #pragma unroll
            for (int q = 0; q < 4; ++q)
                XtB[(rb + q) * 64 + (c - 64)] = f2bs(acc[ct][q] + bj);
        }
    }
}

// K2a: bucket histogram (bucket = t>>2, 25000 buckets, ~64 edges each)
__global__ __launch_bounds__(256) void bucket_count(const int* __restrict__ eidx,
                                                    int* __restrict__ bcnt)
{
    const int i = blockIdx.x * 256 + threadIdx.x;       // quad index
    if (i < N_EDGES / 4) {
        const int4 t4 = reinterpret_cast<const int4*>(eidx + N_EDGES)[i];
        atomicAdd(&bcnt[t4.x >> 2], 1);
        atomicAdd(&bcnt[t4.y >> 2], 1);
        atomicAdd(&bcnt[t4.z >> 2], 1);
        atomicAdd(&bcnt[t4.w >> 2], 1);
    }
}

// K2b: per-block exclusive scan -> outv; block totals -> bsum
__global__ __launch_bounds__(1024) void scan_blocks(const int* __restrict__ in,
                                                    int* __restrict__ outv,
                                                    int* __restrict__ bsum, int n)
{
    __shared__ int wsum[16];
    const int i = blockIdx.x * 1024 + threadIdx.x;
    const int lane = threadIdx.x & 63, wid = threadIdx.x >> 6;
    const int v = (i < n) ? in[i] : 0;
    int s = v;
    #pragma unroll
    for (int d = 1; d < 64; d <<= 1) {
        int u = __shfl_up(s, d);
        if (lane >= d) s += u;
    }
    if (lane == 63) wsum[wid] = s;
    __syncthreads();
    if (wid == 0) {
        int ws = (lane < 16) ? wsum[lane] : 0;
        #pragma unroll
        for (int d = 1; d < 16; d <<= 1) {
            int u = __shfl_up(ws, d);
            if (lane >= d) ws += u;
        }
        if (lane < 16) wsum[lane] = ws;
    }
    __syncthreads();
    const int base = wid ? wsum[wid - 1] : 0;
    if (i < n) outv[i] = base + s - v;
    if (threadIdx.x == 1023) bsum[blockIdx.x] = wsum[15];
}

// K2c: exclusive scan of block sums (nb <= 128)
__global__ __launch_bounds__(128) void scan_partials(int* __restrict__ bsum, int nb)
{
    __shared__ int wsum[2];
    const int i = threadIdx.x;
    const int lane = i & 63, wid = i >> 6;
    const int v = (i < nb) ? bsum[i] : 0;
    int s = v;
    #pragma unroll
    for (int d = 1; d < 64; d <<= 1) {
        int u = __shfl_up(s, d);
        if (lane >= d) s += u;
    }
    if (lane == 63) wsum[wid] = s;
    __syncthreads();
    const int base = wid ? wsum[0] : 0;
    if (i < nb) bsum[i] = base + s - v;
}

// K2d: add block base; init cursor
__global__ __launch_bounds__(1024) void add_base(int* __restrict__ row_,
                                                 const int* __restrict__ bsum,
                                                 int* __restrict__ cursor, int n)
{
    const int i = blockIdx.x * 1024 + threadIdx.x;
    if (i < n) {
        const int r = row_[i] + bsum[blockIdx.x];
        row_[i] = r;
        cursor[i] = r;
    }
}

// K2e: scatter packed edges (s | (t&63)<<20) into bucket regions.
// 25000 tail regions (1.6 MB of lines, 16 entries/line) stay L2-resident while
// only ~1.6 MB/XCD of edge stream passes through -> no line thrash.
__global__ __launch_bounds__(256) void pair_scatter(const int* __restrict__ eidx,
                                                    int* __restrict__ cursor,
                                                    unsigned int* __restrict__ pairs)
{
    const int i = blockIdx.x * 256 + threadIdx.x;       // quad index
    if (i < N_EDGES / 4) {
        const int4 s4 = reinterpret_cast<const int4*>(eidx)[i];
        const int4 t4 = reinterpret_cast<const int4*>(eidx + N_EDGES)[i];
        int p;
        p = atomicAdd(&cursor[t4.x >> 2], 1); pairs[p] = (unsigned)s4.x | ((unsigned)(t4.x & 63) << 20);
        p = atomicAdd(&cursor[t4.y >> 2], 1); pairs[p] = (unsigned)s4.y | ((unsigned)(t4.y & 63) << 20);
        p = atomicAdd(&cursor[t4.z >> 2], 1); pairs[p] = (unsigned)s4.z | ((unsigned)(t4.z & 63) << 20);
        p = atomicAdd(&cursor[t4.w >> 2], 1); pairs[p] = (unsigned)s4.w | ((unsigned)(t4.w & 63) << 20);
    }
}

// K3 (fused): block = 64-node window (16 buckets, contiguous pair range).
// Phase A: accumulate relu(Xs[s]+Xt[t]) into LDS f32 planes (ds_add_f32) + count.
// Phase B: mean + MFMA update MLP + store out. No aggB round-trip.
__global__ __launch_bounds__(256) void agg_update(
    const int* __restrict__ brow, const unsigned int* __restrict__ pairs,
    const unsigned int* __restrict__ Xs32, const unsigned int* __restrict__ Xt32,
    const unsigned short* __restrict__ xB,
    const float* __restrict__ W_upd, const float* __restrict__ b_upd,
    float* __restrict__ out)
{
    __shared__ float accL[64][36];        // plane of even bf16-cols (col c -> 2c)
    __shared__ float accH[64][36];        // plane of odd  bf16-cols (col c -> 2c+1)
    __shared__ unsigned int ubuf[4096];   // phase A: xt rows (2048 uints); phase B: W frags
    __shared__ int cntS[64];
    __shared__ float invS[64];

    const int tid = threadIdx.x;
    const int n0 = blockIdx.x * 64;

    // init acc, cnt; stage Xt rows
    for (int i = tid; i < 64 * 36; i += 256) {
        accL[i / 36][i % 36] = 0.f;
        accH[i / 36][i % 36] = 0.f;
    }
    if (tid < 64) cntS[tid] = 0;
    for (int i = tid; i < 2048; i += 256) {
        const int nn = n0 + (i >> 5);
        ubuf[i] = (nn < N_NODES) ? Xt32[nn * 32 + (i & 31)] : 0u;
    }
    __syncthreads();

    // Phase A: edges [rs, re)
    const int b0 = blockIdx.x * 16;
    const int rs = brow[b0];
    const int re = (b0 + 16 < NBUCK) ? brow[b0 + 16] : N_EDGES;
    const int slot = tid >> 5;            // 0..7 half-waves
    const int c = tid & 31;               // uint column
    int i = rs + slot * 2;
    for (; i + 1 < re; i += 16) {         // 2 edges in flight per half-wave
        const unsigned int p0 = pairs[i], p1 = pairs[i + 1];
        const int s0 = p0 & 0xFFFFF, t0 = p0 >> 20;
        const int s1 = p1 & 0xFFFFF, t1 = p1 >> 20;
        const unsigned int u0 = Xs32[s0 * 32 + c];
        const unsigned int u1 = Xs32[s1 * 32 + c];
        const unsigned int x0 = ubuf[t0 * 32 + c];
        const unsigned int x1 = ubuf[t1 * 32 + c];
        atomicAdd(&accL[t0][c], fmaxf(b2f(u0 & 0xffffu) + b2f(x0 & 0xffffu), 0.f));
        atomicAdd(&accH[t0][c], fmaxf(b2f(u0 >> 16) + b2f(x0 >> 16), 0.f));
        atomicAdd(&accL[t1][c], fmaxf(b2f(u1 & 0xffffu) + b2f(x1 & 0xffffu), 0.f));
        atomicAdd(&accH[t1][c], fmaxf(b2f(u1 >> 16) + b2f(x1 >> 16), 0.f));
        if (c == 0) { atomicAdd(&cntS[t0], 1); atomicAdd(&cntS[t1], 1); }
    }
    if (i < re) {
        const unsigned int p0 = pairs[i];
        const int s0 = p0 & 0xFFFFF, t0 = p0 >> 20;
        const unsigned int u0 = Xs32[s0 * 32 + c];
        const unsigned int x0 = ubuf[t0 * 32 + c];
        atomicAdd(&accL[t0][c], fmaxf(b2f(u0 & 0xffffu) + b2f(x0 & 0xffffu), 0.f));
        atomicAdd(&accH[t0][c], fmaxf(b2f(u0 >> 16) + b2f(x0 >> 16), 0.f));
        if (c == 0) atomicAdd(&cntS[t0], 1);
    }
    __syncthreads();

    // Phase B prep: W fragments into ubuf (overwrites xt), inverse counts
    unsigned short* WBs = reinterpret_cast<unsigned short*>(ubuf);
    for (int ii = tid; ii < 8192; ii += 256) {
        const int j = ii & 7, l = (ii >> 3) & 63, kk = (ii >> 9) & 3, ct = ii >> 11;
        const int k = kk * 32 + ((l >> 4) << 3) + j;
        const int cc = ct * 16 + (l & 15);
        WBs[ii] = f2bs(W_upd[k * 64 + cc]);
    }
    if (tid < 64) {
        const int cn = cntS[tid];
        invS[tid] = (cn > 0) ? 1.0f / (float)cn : 1.0f;
    }
    __syncthreads();

    // Phase B: MFMA update for this block's 64 rows
    const int lane = tid & 63, w = tid >> 6;
    const int r0w = n0 + w * 16;
    if (r0w >= N_NODES) return;

    f32x4 acc4[4];
    #pragma unroll
    for (int ct = 0; ct < 4; ++ct) acc4[ct] = (f32x4){0.f, 0.f, 0.f, 0.f};

    const int r_l = w * 16 + (lane & 15);
    const int rg = n0 + r_l;
    const int rc = (rg < N_NODES) ? rg : (N_NODES - 1);
    const float inv = invS[r_l];

    #pragma unroll
    for (int kk = 0; kk < 4; ++kk) {
        bf16x8 a;
        if (kk < 2) {
            const int off = kk * 32 + ((lane >> 4) << 3);
            a = *reinterpret_cast<const bf16x8*>(&xB[rc * 64 + off]);
        } else {
            const int half = ((kk - 2) * 32 + ((lane >> 4) << 3)) >> 1;  // float col
            const float4 lo = *reinterpret_cast<const float4*>(&accL[r_l][half]);
            const float4 hi = *reinterpret_cast<const float4*>(&accH[r_l][half]);
            a[0] = (short)f2bs(lo.x * inv); a[1] = (short)f2bs(hi.x * inv);
            a[2] = (short)f2bs(lo.y * inv); a[3] = (short)f2bs(hi.y * inv);
            a[4] = (short)f2bs(lo.z * inv); a[5] = (short)f2bs(hi.z * inv);
            a[6] = (short)f2bs(lo.w * inv); a[7] = (short)f2bs(hi.w * inv);
        }
        #pragma unroll
        for (int ct = 0; ct < 4; ++ct) {
            const bf16x8 b = *reinterpret_cast<const bf16x8*>(
                &WBs[(((ct << 2) | kk) * 64 + lane) << 3]);
            acc4[ct] = __builtin_amdgcn_mfma_f32_16x16x32_bf16(a, b, acc4[ct], 0, 0, 0);
        }
    }

    const int rb = n0 + w * 16 + ((lane >> 4) << 2);     // whole 16-row tile < N (N%16==0)
    #pragma unroll
    for (int ct = 0; ct < 4; ++ct) {
        const int cc = ct * 16 + (lane & 15);
        const float bj = b_upd[cc];
        #pragma unroll
        for (int q = 0; q < 4; ++q)
            out[(rb + q) * 64 + cc] = fmaxf(acc4[ct][q] + bj, 0.f);
    }
}

extern "C" void kernel_launch(void* const* d_in, const int* in_sizes, int n_in,
                              void* d_out, int out_size, void* d_ws, size_t ws_size,
                              hipStream_t stream) {
    const float* x     = (const float*)d_in[0];
    const int*   eidx  = (const int*)  d_in[1];   // [2][E] int32
    const float* W_msg = (const float*)d_in[2];
    const float* b_msg = (const float*)d_in[3];
    const float* W_upd = (const float*)d_in[4];
    const float* b_upd = (const float*)d_in[5];
    float* out = (float*)d_out;

    int* bcnt    = (int*)d_ws;                     // [25000]
    int* brow    = bcnt + NBUCK;                   // [25000]
    int* bcursor = brow + NBUCK;                   // [25000]
    int* bsum    = bcursor + NBUCK;                // [32]
    unsigned int* pairs = (unsigned int*)(bsum + 32);          // [E]  6.4 MB
    unsigned short* XsB = (unsigned short*)(pairs + N_EDGES);  // [N][64] bf16
    unsigned short* XtB = XsB + (size_t)N_NODES * DIM;         // [N][64] bf16
    unsigned short* xB  = XtB + (size_t)N_NODES * DIM;         // [N][64] bf16

    const int nodeBlocks = (N_NODES + 63) / 64;       // 1563
    const int quadBlocks = (N_EDGES / 4 + 255) / 256; // 1563
    const int scanBlocks = (NBUCK + 1023) / 1024;     // 25

    node_transform<<<nodeBlocks, 256, 0, stream>>>(x, W_msg, b_msg, XsB, XtB, xB, bcnt);
    bucket_count<<<quadBlocks, 256, 0, stream>>>(eidx, bcnt);
    scan_blocks<<<scanBlocks, 1024, 0, stream>>>(bcnt, brow, bsum, NBUCK);
    scan_partials<<<1, 128, 0, stream>>>(bsum, scanBlocks);
    add_base<<<scanBlocks, 1024, 0, stream>>>(brow, bsum, bcursor, NBUCK);
    pair_scatter<<<quadBlocks, 256, 0, stream>>>(eidx, bcursor, pairs);
    agg_update<<<nodeBlocks, 256, 0, stream>>>(brow, pairs,
        (const unsigned int*)XsB, (const unsigned int*)XtB, xB, W_upd, b_upd, out);
}

// Round 6
// 148.792 us; speedup vs baseline: 5.4784x; 5.4784x over previous
//
#include <hip/hip_runtime.h>
#include <hip/hip_bf16.h>

#define N_NODES 100000
#define N_EDGES 1600000
#define DIM 64
#define NB 196                 // buckets of 512 nodes (t>>9)
#define SMASK 0x1FFFFu         // 17 bits for source id (100000 < 131072)

typedef __attribute__((ext_vector_type(8))) short bf16x8;
typedef __attribute__((ext_vector_type(4))) float f32x4;

__device__ __forceinline__ float b2f(unsigned int u16) {
    return __uint_as_float(u16 << 16);
}
__device__ __forceinline__ unsigned short f2bs(float f) {
    __hip_bfloat16 h = __float2bfloat16(f);
    return *reinterpret_cast<unsigned short*>(&h);
}

// K1 (MFMA): XsB = bf16(x @ Wm[0:64]), XtB = bf16(x @ Wm[64:128] + b), xB = bf16(x).
// Also zeroes bcnt[NB] (ws poisoned; must re-init every call).
__global__ __launch_bounds__(256) void node_transform(
    const float* __restrict__ x, const float* __restrict__ W_msg,
    const float* __restrict__ b_msg,
    unsigned short* __restrict__ XsB, unsigned short* __restrict__ XtB,
    unsigned short* __restrict__ xB, int* __restrict__ bcnt)
{
    __shared__ unsigned short WB[8192];   // [ct(8)][kk(2)][lane(64)][j(8)]
    const int tid = threadIdx.x;
    const int gtid = blockIdx.x * 256 + tid;
    if (gtid < NB) bcnt[gtid] = 0;

    for (int i = tid; i < 8192; i += 256) {
        const int j = i & 7, l = (i >> 3) & 63, kk = (i >> 9) & 1, ct = i >> 10;
        const int k = kk * 32 + ((l >> 4) << 3) + j;     // [0,64)
        const int c = ct * 16 + (l & 15);                // [0,128)
        WB[i] = f2bs(W_msg[(((c >> 6) << 6) + k) * 64 + (c & 63)]);
    }
    __syncthreads();

    const int lane = tid & 63, w = tid >> 6;
    const int r0 = blockIdx.x * 64 + w * 16;
    if (r0 >= N_NODES) return;

    f32x4 acc[8];
    #pragma unroll
    for (int ct = 0; ct < 8; ++ct) acc[ct] = (f32x4){0.f, 0.f, 0.f, 0.f};

    const int r = r0 + (lane & 15);
    #pragma unroll
    for (int kk = 0; kk < 2; ++kk) {
        const int off = kk * 32 + ((lane >> 4) << 3);
        const float4* xp = reinterpret_cast<const float4*>(&x[r * 64 + off]);
        const float4 p0 = xp[0], p1 = xp[1];
        bf16x8 a;
        a[0] = (short)f2bs(p0.x); a[1] = (short)f2bs(p0.y);
        a[2] = (short)f2bs(p0.z); a[3] = (short)f2bs(p0.w);
        a[4] = (short)f2bs(p1.x); a[5] = (short)f2bs(p1.y);
        a[6] = (short)f2bs(p1.z); a[7] = (short)f2bs(p1.w);
        *reinterpret_cast<bf16x8*>(&xB[r * 64 + off]) = a;
        #pragma unroll
        for (int ct = 0; ct < 8; ++ct) {
            const bf16x8 b = *reinterpret_cast<const bf16x8*>(
                &WB[(((ct << 1) | kk) * 64 + lane) << 3]);
            acc[ct] = __builtin_amdgcn_mfma_f32_16x16x32_bf16(a, b, acc[ct], 0, 0, 0);
        }
    }

    const int rb = r0 + ((lane >> 4) << 2);
    #pragma unroll
    for (int ct = 0; ct < 8; ++ct) {
        const int c = ct * 16 + (lane & 15);
        if (c < 64) {
            #pragma unroll
            for (int q = 0; q < 4; ++q)
                XsB[(rb + q) * 64 + c] = f2bs(acc[ct][q]);
        } else {
            const float bj = b_msg[c - 64];
            #pragma unroll
            for (int q = 0; q < 4; ++q)
                XtB[(rb + q) * 64 + (c - 64)] = f2bs(acc[ct][q] + bj);
        }
    }
}

// K2a: bucket histogram via per-block LDS hist (196 buckets = t>>9)
__global__ __launch_bounds__(256) void bucket_hist(const int* __restrict__ eidx,
                                                   int* __restrict__ bcnt)
{
    __shared__ int h[NB];
    if (threadIdx.x < NB) h[threadIdx.x] = 0;
    __syncthreads();
    const int NQ = N_EDGES / 4;
    const int4* t4p = reinterpret_cast<const int4*>(eidx + N_EDGES);
    for (int i = blockIdx.x * 256 + threadIdx.x; i < NQ; i += gridDim.x * 256) {
        const int4 t4 = t4p[i];
        atomicAdd(&h[t4.x >> 9], 1);
        atomicAdd(&h[t4.y >> 9], 1);
        atomicAdd(&h[t4.z >> 9], 1);
        atomicAdd(&h[t4.w >> 9], 1);
    }
    __syncthreads();
    if (threadIdx.x < NB && h[threadIdx.x]) atomicAdd(&bcnt[threadIdx.x], h[threadIdx.x]);
}

// K2b: single-block exclusive scan of bcnt[NB] -> bbase; init bcursor.
__global__ __launch_bounds__(256) void scan196(const int* __restrict__ bcnt,
                                               int* __restrict__ bbase,
                                               int* __restrict__ bcursor)
{
    __shared__ int wsum[4];
    const int tid = threadIdx.x, lane = tid & 63, wid = tid >> 6;
    const int v = (tid < NB) ? bcnt[tid] : 0;
    int s = v;
    #pragma unroll
    for (int d = 1; d < 64; d <<= 1) { int u = __shfl_up(s, d); if (lane >= d) s += u; }
    if (lane == 63) wsum[wid] = s;
    __syncthreads();
    if (wid == 0) {
        int ws = (lane < 4) ? wsum[lane] : 0;
        #pragma unroll
        for (int d = 1; d < 4; d <<= 1) { int u = __shfl_up(ws, d); if (lane >= d) ws += u; }
        if (lane < 4) wsum[lane] = ws;
    }
    __syncthreads();
    const int exc = (wid ? wsum[wid - 1] : 0) + s - v;
    if (tid < NB) { bbase[tid] = exc; bcursor[tid] = exc; }
    if (tid == 0) bbase[NB] = N_EDGES;
}

// K2c: LDS-staged partition. Tile = 4096 edges/block. Rank in LDS, reserve one
// global cursor slab per bucket, regroup in LDS, flush with coalesced runs
// (avg 21 contiguous entries) -> line-granular writes, no 16x amplification.
// Packed entry: s | (t&511)<<17.
__global__ __launch_bounds__(256) void partition(const int* __restrict__ eidx,
                                                 int* __restrict__ bcursor,
                                                 unsigned int* __restrict__ pairs)
{
    __shared__ unsigned int sbuf[4096];
    __shared__ int dbase[4096];
    __shared__ int tcnt[NB], toff[NB], gpos[NB];
    __shared__ int wsum[4];
    const int tid = threadIdx.x, lane = tid & 63, wid = tid >> 6;
    const int base = blockIdx.x * 4096;
    const int tcount = min(4096, N_EDGES - base);
    if (tid < NB) tcnt[tid] = 0;
    __syncthreads();

    unsigned int pk[16]; int bb[16]; int rk[16];
    #pragma unroll
    for (int j = 0; j < 16; ++j) {
        const int idx = base + j * 256 + tid;
        bb[j] = -1;
        if (idx < N_EDGES) {
            const int sv = eidx[idx];
            const int tv = eidx[N_EDGES + idx];
            bb[j] = tv >> 9;
            pk[j] = (unsigned)sv | ((unsigned)(tv & 511) << 17);
            rk[j] = atomicAdd(&tcnt[bb[j]], 1);
        }
    }
    __syncthreads();

    const int v = (tid < NB) ? tcnt[tid] : 0;
    int s = v;
    #pragma unroll
    for (int d = 1; d < 64; d <<= 1) { int u = __shfl_up(s, d); if (lane >= d) s += u; }
    if (lane == 63) wsum[wid] = s;
    __syncthreads();
    if (wid == 0) {
        int ws = (lane < 4) ? wsum[lane] : 0;
        #pragma unroll
        for (int d = 1; d < 4; d <<= 1) { int u = __shfl_up(ws, d); if (lane >= d) ws += u; }
        if (lane < 4) wsum[lane] = ws;
    }
    __syncthreads();
    const int exc = (wid ? wsum[wid - 1] : 0) + s - v;
    if (tid < NB) {
        toff[tid] = exc;
        gpos[tid] = v ? atomicAdd(&bcursor[tid], v) : 0;
    }
    __syncthreads();

    #pragma unroll
    for (int j = 0; j < 16; ++j) {
        if (bb[j] >= 0) {
            const int l = toff[bb[j]] + rk[j];
            sbuf[l]  = pk[j];
            dbase[l] = gpos[bb[j]] + rk[j];
        }
    }
    __syncthreads();
    for (int i = tid; i < tcount; i += 256)
        pairs[dbase[i]] = sbuf[i];
}

// K2d: per-bucket counting sort in LDS -> node-ordered csr + row/deg.
// Global scatter confined to the block's own contiguous ~32KB segment
// (single-XCD L2-resident, single writer -> ~1x writeback).
__global__ __launch_bounds__(512) void bucket_sort(const int* __restrict__ bbase,
                                                   const unsigned int* __restrict__ pairs,
                                                   int* __restrict__ csr,
                                                   int* __restrict__ deg,
                                                   int* __restrict__ row)
{
    __shared__ unsigned int ebuf[12288];      // 48 KB (bucket avg ~8163, 45-sigma margin)
    __shared__ unsigned short rbuf[12288];    // 24 KB
    __shared__ int ncnt[512], noff[512];
    __shared__ int wsum[8];
    const int tid = threadIdx.x, lane = tid & 63, wid = tid >> 6;
    const int b = blockIdx.x;
    const int s0 = bbase[b], s1 = bbase[b + 1];
    const int cnt = s1 - s0;
    ncnt[tid] = 0;
    __syncthreads();

    for (int i = tid; i < cnt; i += 512) {
        const unsigned int p = pairs[s0 + i];
        ebuf[i] = p;
        rbuf[i] = (unsigned short)atomicAdd(&ncnt[p >> 17], 1);
    }
    __syncthreads();

    const int v = ncnt[tid];
    int s = v;
    #pragma unroll
    for (int d = 1; d < 64; d <<= 1) { int u = __shfl_up(s, d); if (lane >= d) s += u; }
    if (lane == 63) wsum[wid] = s;
    __syncthreads();
    if (wid == 0) {
        int ws = (lane < 8) ? wsum[lane] : 0;
        #pragma unroll
        for (int d = 1; d < 8; d <<= 1) { int u = __shfl_up(ws, d); if (lane >= d) ws += u; }
        if (lane < 8) wsum[lane] = ws;
    }
    __syncthreads();
    const int exc = (wid ? wsum[wid - 1] : 0) + s - v;
    noff[tid] = exc;
    const int n = b * 512 + tid;
    if (n < N_NODES) { deg[n] = v; row[n] = s0 + exc; }
    __syncthreads();

    for (int i = tid; i < cnt; i += 512) {
        const unsigned int p = ebuf[i];
        csr[s0 + noff[p >> 17] + (int)rbuf[i]] = (int)(p & SMASK);
    }
}

// K3: wave per node; half-waves gather 4 edges each in flight (uint = 2 bf16 cols).
__global__ __launch_bounds__(256) void aggregate(
    const int* __restrict__ row, const int* __restrict__ deg,
    const int* __restrict__ csr,
    const unsigned int* __restrict__ Xs32, const unsigned int* __restrict__ Xt32,
    unsigned int* __restrict__ agg32)
{
    const int n = blockIdx.x * 4 + (threadIdx.x >> 6);
    const int lane = threadIdx.x & 63;
    if (n >= N_NODES) return;
    const int c = lane & 31;
    const int h = lane >> 5;
    const int start = row[n], d = deg[n];
    const unsigned int xt = Xt32[n * 32 + c];
    const float t0 = b2f(xt & 0xffffu), t1 = b2f(xt >> 16);
    float a0 = 0.f, a1 = 0.f;
    int i = 0;
    for (; i + 8 <= d; i += 8) {          // 8 edges/iter: 4 per half-wave in flight
        const int sA = csr[start + i + h];
        const int sB = csr[start + i + 2 + h];
        const int sC = csr[start + i + 4 + h];
        const int sD = csr[start + i + 6 + h];
        const unsigned int uA = Xs32[sA * 32 + c];
        const unsigned int uB = Xs32[sB * 32 + c];
        const unsigned int uC = Xs32[sC * 32 + c];
        const unsigned int uD = Xs32[sD * 32 + c];
        a0 += fmaxf(b2f(uA & 0xffffu) + t0, 0.f) + fmaxf(b2f(uB & 0xffffu) + t0, 0.f)
            + fmaxf(b2f(uC & 0xffffu) + t0, 0.f) + fmaxf(b2f(uD & 0xffffu) + t0, 0.f);
        a1 += fmaxf(b2f(uA >> 16) + t1, 0.f) + fmaxf(b2f(uB >> 16) + t1, 0.f)
            + fmaxf(b2f(uC >> 16) + t1, 0.f) + fmaxf(b2f(uD >> 16) + t1, 0.f);
    }
    for (; i + 2 <= d; i += 2) {
        const int sv = csr[start + i + h];
        const unsigned int u = Xs32[sv * 32 + c];
        a0 += fmaxf(b2f(u & 0xffffu) + t0, 0.f);
        a1 += fmaxf(b2f(u >> 16) + t1, 0.f);
    }
    if (h == 0 && i < d) {
        const int sv = csr[start + i];
        const unsigned int u = Xs32[sv * 32 + c];
        a0 += fmaxf(b2f(u & 0xffffu) + t0, 0.f);
        a1 += fmaxf(b2f(u >> 16) + t1, 0.f);
    }
    a0 += __shfl_xor(a0, 32);
    a1 += __shfl_xor(a1, 32);
    if (h == 0) {
        const float inv = (d > 0) ? 1.0f / (float)d : 0.f;
        agg32[n * 32 + c] = (unsigned int)f2bs(a0 * inv) |
                            ((unsigned int)f2bs(a1 * inv) << 16);
    }
}

// K4 (MFMA): out = relu([xB | aggB] @ W_upd + b_upd). K=128 (4 steps), 4 col-tiles.
__global__ __launch_bounds__(256) void node_update(
    const unsigned short* __restrict__ xB, const unsigned short* __restrict__ aggB,
    const float* __restrict__ W_upd, const float* __restrict__ b_upd,
    float* __restrict__ out)
{
    __shared__ unsigned short WB[8192];   // [ct(4)][kk(4)][lane(64)][j(8)]
    const int tid = threadIdx.x;
    for (int i = tid; i < 8192; i += 256) {
        const int j = i & 7, l = (i >> 3) & 63, kk = (i >> 9) & 3, ct = i >> 11;
        const int k = kk * 32 + ((l >> 4) << 3) + j;
        const int c = ct * 16 + (l & 15);
        WB[i] = f2bs(W_upd[k * 64 + c]);
    }
    __syncthreads();

    const int lane = tid & 63, w = tid >> 6;
    const int r0 = blockIdx.x * 64 + w * 16;
    if (r0 >= N_NODES) return;

    f32x4 acc[4];
    #pragma unroll
    for (int ct = 0; ct < 4; ++ct) acc[ct] = (f32x4){0.f, 0.f, 0.f, 0.f};

    const int r = r0 + (lane & 15);
    #pragma unroll
    for (int kk = 0; kk < 4; ++kk) {
        const int off = kk * 32 + ((lane >> 4) << 3);
        const unsigned short* src = (off < 64) ? &xB[r * 64 + off]
                                               : &aggB[r * 64 + off - 64];
        const bf16x8 a = *reinterpret_cast<const bf16x8*>(src);
        #pragma unroll
        for (int ct = 0; ct < 4; ++ct) {
            const bf16x8 b = *reinterpret_cast<const bf16x8*>(
                &WB[(((ct << 2) | kk) * 64 + lane) << 3]);
            acc[ct] = __builtin_amdgcn_mfma_f32_16x16x32_bf16(a, b, acc[ct], 0, 0, 0);
        }
    }

    const int rb = r0 + ((lane >> 4) << 2);
    #pragma unroll
    for (int ct = 0; ct < 4; ++ct) {
        const int c = ct * 16 + (lane & 15);
        const float bj = b_upd[c];
        #pragma unroll
        for (int q = 0; q < 4; ++q)
            out[(rb + q) * 64 + c] = fmaxf(acc[ct][q] + bj, 0.f);
    }
}

extern "C" void kernel_launch(void* const* d_in, const int* in_sizes, int n_in,
                              void* d_out, int out_size, void* d_ws, size_t ws_size,
                              hipStream_t stream) {
    const float* x     = (const float*)d_in[0];
    const int*   eidx  = (const int*)  d_in[1];   // [2][E] int32
    const float* W_msg = (const float*)d_in[2];
    const float* b_msg = (const float*)d_in[3];
    const float* W_upd = (const float*)d_in[4];
    const float* b_upd = (const float*)d_in[5];
    float* out = (float*)d_out;

    int* bcnt    = (int*)d_ws;                     // [196]
    int* bbase   = bcnt + NB;                      // [197] (+pad)
    int* bcursor = bbase + 200;                    // [196]
    int* deg     = bcursor + NB;                   // [N]
    int* row     = deg + N_NODES;                  // [N]
    int* csr     = row + N_NODES;                  // [E]
    unsigned int* pairs = (unsigned int*)(csr + N_EDGES);      // [E]
    unsigned short* XsB  = (unsigned short*)(pairs + N_EDGES); // [N][64] bf16
    unsigned short* XtB  = XsB + (size_t)N_NODES * DIM;        // [N][64] bf16
    unsigned short* xB   = XtB + (size_t)N_NODES * DIM;        // [N][64] bf16
    unsigned short* aggB = xB  + (size_t)N_NODES * DIM;        // [N][64] bf16

    const int nodeBlocks = (N_NODES + 63) / 64;       // 1563
    const int partBlocks = (N_EDGES + 4095) / 4096;   // 391

    node_transform<<<nodeBlocks, 256, 0, stream>>>(x, W_msg, b_msg, XsB, XtB, xB, bcnt);
    bucket_hist<<<256, 256, 0, stream>>>(eidx, bcnt);
    scan196<<<1, 256, 0, stream>>>(bcnt, bbase, bcursor);
    partition<<<partBlocks, 256, 0, stream>>>(eidx, bcursor, pairs);
    bucket_sort<<<NB, 512, 0, stream>>>(bbase, pairs, csr, deg, row);
    aggregate<<<(N_NODES + 3) / 4, 256, 0, stream>>>(row, deg, csr,
        (const unsigned int*)XsB, (const unsigned int*)XtB, (unsigned int*)aggB);
    node_update<<<nodeBlocks, 256, 0, stream>>>(xB, aggB, W_upd, b_upd, out);
}

// Round 7
// 122.388 us; speedup vs baseline: 6.6603x; 1.2157x over previous
//
#include <hip/hip_runtime.h>
#include <hip/hip_bf16.h>

#define N_NODES 100000
#define N_EDGES 1600000
#define DIM 64
#define NB 196                 // buckets of 512 nodes (t>>9)
#define CAP 9216               // slab capacity (mean 8192 + 11 sigma; fixed input)
#define SMASK 0x1FFFFu         // 17 bits for source id

typedef __attribute__((ext_vector_type(8))) short bf16x8;
typedef __attribute__((ext_vector_type(4))) float f32x4;
typedef __attribute__((ext_vector_type(2))) float f32x2;

__device__ __forceinline__ float b2f(unsigned int u16) {
    return __uint_as_float(u16 << 16);
}
__device__ __forceinline__ unsigned short f2bs(float f) {
    __hip_bfloat16 h = __float2bfloat16(f);
    return *reinterpret_cast<unsigned short*>(&h);
}

// K1 (MFMA): Xs8 = fp8e4m3(x @ Wm[0:64]) in permuted uint layout
//            ([row][16] uint c -> cols {c,16+c,32+c,48+c}),
//            XtP = bf16(x @ Wm[64:128] + b) in permuted uint2 layout,
//            xB  = bf16(x) row-major.
// Also inits bcursor slab bases (ws poisoned; must re-init every call).
__global__ __launch_bounds__(256) void node_transform(
    const float* __restrict__ x, const float* __restrict__ W_msg,
    const float* __restrict__ b_msg,
    unsigned int* __restrict__ Xs8, uint2* __restrict__ XtP,
    unsigned short* __restrict__ xB, int* __restrict__ bcursor)
{
    __shared__ unsigned short WB[8192];   // [ct(8)][kk(2)][lane(64)][j(8)]
    const int tid = threadIdx.x;
    const int gtid = blockIdx.x * 256 + tid;
    if (gtid < NB) bcursor[gtid] = gtid * CAP;

    for (int i = tid; i < 8192; i += 256) {
        const int j = i & 7, l = (i >> 3) & 63, kk = (i >> 9) & 1, ct = i >> 10;
        const int k = kk * 32 + ((l >> 4) << 3) + j;     // [0,64)
        const int c = ct * 16 + (l & 15);                // [0,128)
        WB[i] = f2bs(W_msg[(((c >> 6) << 6) + k) * 64 + (c & 63)]);
    }
    __syncthreads();

    const int lane = tid & 63, w = tid >> 6;
    const int r0 = blockIdx.x * 64 + w * 16;
    if (r0 >= N_NODES) return;                            // N%16==0

    f32x4 acc[8];
    #pragma unroll
    for (int ct = 0; ct < 8; ++ct) acc[ct] = (f32x4){0.f, 0.f, 0.f, 0.f};

    const int r = r0 + (lane & 15);
    #pragma unroll
    for (int kk = 0; kk < 2; ++kk) {
        const int off = kk * 32 + ((lane >> 4) << 3);
        const float4* xp = reinterpret_cast<const float4*>(&x[r * 64 + off]);
        const float4 p0 = xp[0], p1 = xp[1];
        bf16x8 a;
        a[0] = (short)f2bs(p0.x); a[1] = (short)f2bs(p0.y);
        a[2] = (short)f2bs(p0.z); a[3] = (short)f2bs(p0.w);
        a[4] = (short)f2bs(p1.x); a[5] = (short)f2bs(p1.y);
        a[6] = (short)f2bs(p1.z); a[7] = (short)f2bs(p1.w);
        *reinterpret_cast<bf16x8*>(&xB[r * 64 + off]) = a;
        #pragma unroll
        for (int ct = 0; ct < 8; ++ct) {
            const bf16x8 b = *reinterpret_cast<const bf16x8*>(
                &WB[(((ct << 1) | kk) * 64 + lane) << 3]);
            acc[ct] = __builtin_amdgcn_mfma_f32_16x16x32_bf16(a, b, acc[ct], 0, 0, 0);
        }
    }

    // C/D: col = ct*16 + (lane&15), row = rb + q  [m89-verified]
    const int fr = lane & 15;
    const int rb = r0 + ((lane >> 4) << 2);
    const float bj0 = b_msg[fr],      bj1 = b_msg[16 + fr];
    const float bj2 = b_msg[32 + fr], bj3 = b_msg[48 + fr];
    #pragma unroll
    for (int q = 0; q < 4; ++q) {
        unsigned int wpk = 0;
        wpk = (unsigned)__builtin_amdgcn_cvt_pk_fp8_f32(acc[0][q], acc[1][q], (int)wpk, false);
        wpk = (unsigned)__builtin_amdgcn_cvt_pk_fp8_f32(acc[2][q], acc[3][q], (int)wpk, true);
        Xs8[(rb + q) * 16 + fr] = wpk;
        uint2 v;
        v.x = (unsigned)f2bs(acc[4][q] + bj0) | ((unsigned)f2bs(acc[5][q] + bj1) << 16);
        v.y = (unsigned)f2bs(acc[6][q] + bj2) | ((unsigned)f2bs(acc[7][q] + bj3) << 16);
        XtP[(rb + q) * 16 + fr] = v;
    }
}

// K2: LDS-staged partition into fixed slabs (bucket b -> pairs[b*CAP ...)).
// Tile = 4096 edges/block: LDS rank, one cursor reservation per bucket,
// LDS regroup, coalesced flush (avg 21-entry runs -> line-granular writes).
__global__ __launch_bounds__(256) void partition(const int* __restrict__ eidx,
                                                 int* __restrict__ bcursor,
                                                 unsigned int* __restrict__ pairs)
{
    __shared__ unsigned int sbuf[4096];
    __shared__ int dbase[4096];
    __shared__ int tcnt[NB], toff[NB], gpos[NB];
    __shared__ int wsum[4];
    const int tid = threadIdx.x, lane = tid & 63, wid = tid >> 6;
    const int base = blockIdx.x * 4096;
    const int tcount = min(4096, N_EDGES - base);
    if (tid < NB) tcnt[tid] = 0;
    __syncthreads();

    unsigned int pk[16]; int bb[16]; int rk[16];
    #pragma unroll
    for (int j = 0; j < 16; ++j) {
        const int idx = base + j * 256 + tid;
        bb[j] = -1;
        if (idx < N_EDGES) {
            const int sv = eidx[idx];
            const int tv = eidx[N_EDGES + idx];
            bb[j] = tv >> 9;
            pk[j] = (unsigned)sv | ((unsigned)(tv & 511) << 17);
            rk[j] = atomicAdd(&tcnt[bb[j]], 1);
        }
    }
    __syncthreads();

    const int v = (tid < NB) ? tcnt[tid] : 0;
    int s = v;
    #pragma unroll
    for (int d = 1; d < 64; d <<= 1) { int u = __shfl_up(s, d); if (lane >= d) s += u; }
    if (lane == 63) wsum[wid] = s;
    __syncthreads();
    if (wid == 0) {
        int ws = (lane < 4) ? wsum[lane] : 0;
        #pragma unroll
        for (int d = 1; d < 4; d <<= 1) { int u = __shfl_up(ws, d); if (lane >= d) ws += u; }
        if (lane < 4) wsum[lane] = ws;
    }
    __syncthreads();
    const int exc = (wid ? wsum[wid - 1] : 0) + s - v;
    if (tid < NB) {
        toff[tid] = exc;
        gpos[tid] = v ? atomicAdd(&bcursor[tid], v) : 0;
    }
    __syncthreads();

    #pragma unroll
    for (int j = 0; j < 16; ++j) {
        if (bb[j] >= 0) {
            const int l = toff[bb[j]] + rk[j];
            sbuf[l]  = pk[j];
            dbase[l] = gpos[bb[j]] + rk[j];
        }
    }
    __syncthreads();
    for (int i = tid; i < tcount; i += 256)
        pairs[dbase[i]] = sbuf[i];
}

// K3: per-bucket counting sort in LDS -> node-ordered csr (slab) + row/deg.
__global__ __launch_bounds__(512) void bucket_sort(const int* __restrict__ bcursor,
                                                   const unsigned int* __restrict__ pairs,
                                                   int* __restrict__ csr,
                                                   int* __restrict__ deg,
                                                   int* __restrict__ row)
{
    __shared__ unsigned int ebuf[CAP];        // 36 KB
    __shared__ unsigned short rbuf[CAP];      // 18 KB
    __shared__ int ncnt[512], noff[512];
    __shared__ int wsum[8];
    const int tid = threadIdx.x, lane = tid & 63, wid = tid >> 6;
    const int b = blockIdx.x;
    const int s0 = b * CAP;
    const int cnt = bcursor[b] - s0;
    ncnt[tid] = 0;
    __syncthreads();

    for (int i = tid; i < cnt; i += 512) {
        const unsigned int p = pairs[s0 + i];
        ebuf[i] = p;
        rbuf[i] = (unsigned short)atomicAdd(&ncnt[p >> 17], 1);
    }
    __syncthreads();

    const int v = ncnt[tid];
    int s = v;
    #pragma unroll
    for (int d = 1; d < 64; d <<= 1) { int u = __shfl_up(s, d); if (lane >= d) s += u; }
    if (lane == 63) wsum[wid] = s;
    __syncthreads();
    if (wid == 0) {
        int ws = (lane < 8) ? wsum[lane] : 0;
        #pragma unroll
        for (int d = 1; d < 8; d <<= 1) { int u = __shfl_up(ws, d); if (lane >= d) ws += u; }
        if (lane < 8) wsum[lane] = ws;
    }
    __syncthreads();
    const int exc = (wid ? wsum[wid - 1] : 0) + s - v;
    noff[tid] = exc;
    const int n = b * 512 + tid;
    if (n < N_NODES) { deg[n] = v; row[n] = s0 + exc; }
    __syncthreads();

    for (int i = tid; i < cnt; i += 512) {
        const unsigned int p = ebuf[i];
        csr[s0 + noff[p >> 17] + (int)rbuf[i]] = (int)(p & SMASK);
    }
}

__device__ __forceinline__ void acc_fp8(unsigned int u,
    float t0, float t1, float t2, float t3,
    float& a0, float& a1, float& a2, float& a3)
{
    const f32x2 lo = __builtin_amdgcn_cvt_pk_f32_fp8(u, false);
    const f32x2 hi = __builtin_amdgcn_cvt_pk_f32_fp8(u, true);
    a0 += fmaxf(lo.x + t0, 0.f);
    a1 += fmaxf(lo.y + t1, 0.f);
    a2 += fmaxf(hi.x + t2, 0.f);
    a3 += fmaxf(hi.y + t3, 0.f);
}

// K4: wave per node; quarter-waves (16 lanes) process one edge each,
// 4 gathers in flight per quarter. 64 B fp8 row per gather.
__global__ __launch_bounds__(256) void aggregate(
    const int* __restrict__ row, const int* __restrict__ deg,
    const int* __restrict__ csr,
    const unsigned int* __restrict__ Xs8, const uint2* __restrict__ XtP,
    uint2* __restrict__ aggP)
{
    const int n = blockIdx.x * 4 + (threadIdx.x >> 6);
    const int lane = threadIdx.x & 63;
    if (n >= N_NODES) return;
    const int c = lane & 15, q = lane >> 4;
    const int start = row[n], d = deg[n];
    const uint2 tp = XtP[n * 16 + c];
    const float t0 = b2f(tp.x & 0xffffu), t1 = b2f(tp.x >> 16);
    const float t2 = b2f(tp.y & 0xffffu), t3 = b2f(tp.y >> 16);
    float a0 = 0.f, a1 = 0.f, a2 = 0.f, a3 = 0.f;
    int i = 0;
    for (; i + 16 <= d; i += 16) {        // 16 edges/iter: 4 per quarter in flight
        const int s0 = csr[start + i + q];
        const int s1 = csr[start + i + 4 + q];
        const int s2 = csr[start + i + 8 + q];
        const int s3 = csr[start + i + 12 + q];
        const unsigned int u0 = Xs8[s0 * 16 + c];
        const unsigned int u1 = Xs8[s1 * 16 + c];
        const unsigned int u2 = Xs8[s2 * 16 + c];
        const unsigned int u3 = Xs8[s3 * 16 + c];
        acc_fp8(u0, t0, t1, t2, t3, a0, a1, a2, a3);
        acc_fp8(u1, t0, t1, t2, t3, a0, a1, a2, a3);
        acc_fp8(u2, t0, t1, t2, t3, a0, a1, a2, a3);
        acc_fp8(u3, t0, t1, t2, t3, a0, a1, a2, a3);
    }
    for (; i + 4 <= d; i += 4) {
        const unsigned int u = Xs8[csr[start + i + q] * 16 + c];
        acc_fp8(u, t0, t1, t2, t3, a0, a1, a2, a3);
    }
    const int rem = d - i;                // 0..3
    if (q < rem) {
        const unsigned int u = Xs8[csr[start + i + q] * 16 + c];
        acc_fp8(u, t0, t1, t2, t3, a0, a1, a2, a3);
    }
    a0 += __shfl_xor(a0, 16); a0 += __shfl_xor(a0, 32);
    a1 += __shfl_xor(a1, 16); a1 += __shfl_xor(a1, 32);
    a2 += __shfl_xor(a2, 16); a2 += __shfl_xor(a2, 32);
    a3 += __shfl_xor(a3, 16); a3 += __shfl_xor(a3, 32);
    if (q == 0) {
        const float inv = (d > 0) ? 1.0f / (float)d : 0.f;
        uint2 v;
        v.x = (unsigned)f2bs(a0 * inv) | ((unsigned)f2bs(a1 * inv) << 16);
        v.y = (unsigned)f2bs(a2 * inv) | ((unsigned)f2bs(a3 * inv) << 16);
        aggP[n * 16 + c] = v;
    }
}

// K5 (MFMA): out = relu([xB | aggP] @ W_upd + b_upd). K=128, 4 col-tiles.
// kk<2 reads xB row-major (k = kk*32+hi*8+j); kk>=2 reads aggP permuted layout
// (k = 64 + 16*(j&3) + (kk-2)*8 + 2*hi + (j>>2)); B staging mirrors both maps.
__global__ __launch_bounds__(256) void node_update(
    const unsigned short* __restrict__ xB, const uint2* __restrict__ aggP,
    const float* __restrict__ W_upd, const float* __restrict__ b_upd,
    float* __restrict__ out)
{
    __shared__ unsigned short WB[8192];   // [ct(4)][kk(4)][lane(64)][j(8)]
    const int tid = threadIdx.x;
    for (int i = tid; i < 8192; i += 256) {
        const int j = i & 7, l = (i >> 3) & 63, kk = (i >> 9) & 3, ct = i >> 11;
        const int hi = l >> 4;
        int k;
        if (kk < 2) k = kk * 32 + (hi << 3) + j;
        else        k = 64 + ((j & 3) << 4) + ((kk - 2) << 3) + (hi << 1) + (j >> 2);
        const int c = ct * 16 + (l & 15);
        WB[i] = f2bs(W_upd[k * 64 + c]);
    }
    __syncthreads();

    const int lane = tid & 63, w = tid >> 6;
    const int r0 = blockIdx.x * 64 + w * 16;
    if (r0 >= N_NODES) return;

    f32x4 acc[4];
    #pragma unroll
    for (int ct = 0; ct < 4; ++ct) acc[ct] = (f32x4){0.f, 0.f, 0.f, 0.f};

    const int r = r0 + (lane & 15);
    const int hi = lane >> 4;
    #pragma unroll
    for (int kk = 0; kk < 4; ++kk) {
        bf16x8 a;
        if (kk < 2) {
            a = *reinterpret_cast<const bf16x8*>(&xB[r * 64 + kk * 32 + (hi << 3)]);
        } else {
            a = *reinterpret_cast<const bf16x8*>(
                &aggP[r * 16 + ((kk - 2) << 3) + (hi << 1)]);
        }
        #pragma unroll
        for (int ct = 0; ct < 4; ++ct) {
            const bf16x8 b = *reinterpret_cast<const bf16x8*>(
                &WB[(((ct << 2) | kk) * 64 + lane) << 3]);
            acc[ct] = __builtin_amdgcn_mfma_f32_16x16x32_bf16(a, b, acc[ct], 0, 0, 0);
        }
    }

    const int rb = r0 + (hi << 2);
    #pragma unroll
    for (int ct = 0; ct < 4; ++ct) {
        const int c = ct * 16 + (lane & 15);
        const float bj = b_upd[c];
        #pragma unroll
        for (int q = 0; q < 4; ++q)
            out[(rb + q) * 64 + c] = fmaxf(acc[ct][q] + bj, 0.f);
    }
}

extern "C" void kernel_launch(void* const* d_in, const int* in_sizes, int n_in,
                              void* d_out, int out_size, void* d_ws, size_t ws_size,
                              hipStream_t stream) {
    const float* x     = (const float*)d_in[0];
    const int*   eidx  = (const int*)  d_in[1];   // [2][E] int32
    const float* W_msg = (const float*)d_in[2];
    const float* b_msg = (const float*)d_in[3];
    const float* W_upd = (const float*)d_in[4];
    const float* b_upd = (const float*)d_in[5];
    float* out = (float*)d_out;

    int* deg     = (int*)d_ws;                         // [N]
    int* row     = deg + N_NODES;                      // [N]
    int* bcursor = row + N_NODES;                      // [256 pad]
    unsigned int* pairs = (unsigned int*)(bcursor + 256);   // [NB*CAP] 7.2 MB
    int* csr     = (int*)(pairs + NB * CAP);                // [NB*CAP] 7.2 MB
    unsigned int* Xs8 = (unsigned int*)(csr + NB * CAP);    // [N][16] uint fp8 6.4 MB
    uint2* XtP   = (uint2*)(Xs8 + (size_t)N_NODES * 16);    // [N][16] uint2 bf16 12.8 MB
    unsigned short* xB = (unsigned short*)(XtP + (size_t)N_NODES * 16); // [N][64] bf16
    uint2* aggP  = (uint2*)(xB + (size_t)N_NODES * DIM);    // [N][16] uint2 bf16 12.8 MB

    const int nodeBlocks = (N_NODES + 63) / 64;       // 1563
    const int partBlocks = (N_EDGES + 4095) / 4096;   // 391

    node_transform<<<nodeBlocks, 256, 0, stream>>>(x, W_msg, b_msg, Xs8, XtP, xB, bcursor);
    partition<<<partBlocks, 256, 0, stream>>>(eidx, bcursor, pairs);
    bucket_sort<<<NB, 512, 0, stream>>>(bcursor, pairs, csr, deg, row);
    aggregate<<<(N_NODES + 3) / 4, 256, 0, stream>>>(row, deg, csr,
        Xs8, XtP, aggP);
    node_update<<<nodeBlocks, 256, 0, stream>>>(xB, aggP, W_upd, b_upd, out);
}